// Round 5
// baseline (440.498 us; speedup 1.0000x reference)
//
#include <hip/hip_runtime.h>

// Dynamic per-group (G=128) asymmetric int8 fake-quantize, fp32 in/out.
// 8192x8192 fp32; groups = 128 contiguous floats = 32 float4s.
// Mapping: 8 consecutive lanes own one group; each lane loads float4s
// l, l+8, l+16, l+24 of the group (8-lane clusters read 128B contiguous
// segments -> fully coalesced). 4 independent loads/thread for MLP.
// Min/max reduction: 3-level shfl_xor butterfly (masks 1,2,4 = within-row
// DPP, pure VALU, no DS pipe).
// One IEEE divide per group for inv_scale; dequant folded to a single FMA.

typedef float f32x4 __attribute__((ext_vector_type(4)));

constexpr float QMIN = -128.0f;
constexpr float QMAX = 127.0f;
constexpr float EPSF = 1.1920928955078125e-07f;  // fp32 eps

__device__ __forceinline__ float min4(f32x4 v) {
  return fminf(fminf(v.x, v.y), fminf(v.z, v.w));
}
__device__ __forceinline__ float max4(f32x4 v) {
  return fmaxf(fmaxf(v.x, v.y), fmaxf(v.z, v.w));
}

__global__ __launch_bounds__(256) void dsq_kernel(
    const float* __restrict__ x, float* __restrict__ out, int n16) {
  const f32x4* __restrict__ x4 = reinterpret_cast<const f32x4*>(x);
  f32x4* __restrict__ o4 = reinterpret_cast<f32x4*>(out);

  int t = blockIdx.x * blockDim.x + threadIdx.x;
  int nthreads = gridDim.x * blockDim.x;  // multiple of 8 -> lane/group map stable

  for (int p = t; p < n16; p += nthreads) {
    // group g = p >> 3 ; lane-in-group l = p & 7 ; float4 base index
    int base = ((p >> 3) << 5) + (p & 7);
    f32x4 v0 = x4[base];
    f32x4 v1 = x4[base + 8];
    f32x4 v2 = x4[base + 16];
    f32x4 v3 = x4[base + 24];

    float mn = fminf(fminf(min4(v0), min4(v1)), fminf(min4(v2), min4(v3)));
    float mx = fmaxf(fmaxf(max4(v0), max4(v1)), fmaxf(max4(v2), max4(v3)));

    // butterfly across the 8 lanes owning this group (DPP-able masks only)
    #pragma unroll
    for (int m = 1; m < 8; m <<= 1) {
      mn = fminf(mn, __shfl_xor(mn, m, 64));
      mx = fmaxf(mx, __shfl_xor(mx, m, 64));
    }

    // observer always includes zero (asymmetric affine)
    mn = fminf(mn, 0.0f);
    mx = fmaxf(mx, 0.0f);

    float scale = fmaxf((mx - mn) * (1.0f / 255.0f), EPSF);
    float inv = 1.0f / scale;  // one IEEE divide per group
    float zp = fminf(fmaxf(rintf(QMIN - mn / scale), QMIN), QMAX);
    float nzs = -zp * scale;  // dequant: o = q*scale - zp*scale = fma(q,scale,nzs)

    f32x4 o0, o1, o2, o3;
    #define QDQ(e) fmaf(fminf(fmaxf(rintf((e) * inv) + zp, QMIN), QMAX), scale, nzs)
    o0.x = QDQ(v0.x); o0.y = QDQ(v0.y); o0.z = QDQ(v0.z); o0.w = QDQ(v0.w);
    o1.x = QDQ(v1.x); o1.y = QDQ(v1.y); o1.z = QDQ(v1.z); o1.w = QDQ(v1.w);
    o2.x = QDQ(v2.x); o2.y = QDQ(v2.y); o2.z = QDQ(v2.z); o2.w = QDQ(v2.w);
    o3.x = QDQ(v3.x); o3.y = QDQ(v3.y); o3.z = QDQ(v3.z); o3.w = QDQ(v3.w);
    #undef QDQ

    __builtin_nontemporal_store(o0, &o4[base]);
    __builtin_nontemporal_store(o1, &o4[base + 8]);
    __builtin_nontemporal_store(o2, &o4[base + 16]);
    __builtin_nontemporal_store(o3, &o4[base + 24]);
  }
}

extern "C" void kernel_launch(void* const* d_in, const int* in_sizes, int n_in,
                              void* d_out, int out_size, void* d_ws, size_t ws_size,
                              hipStream_t stream) {
  const float* x = (const float*)d_in[0];
  float* out = (float*)d_out;
  int n16 = out_size / 16;  // 16 floats per thread-iteration

  // full residency: 2048 blocks x 256 thr = 524288 threads; 8 iters each
  dsq_kernel<<<2048, 256, 0, stream>>>(x, out, n16);
}

// Round 6
// 432.478 us; speedup vs baseline: 1.0185x; 1.0185x over previous
//
#include <hip/hip_runtime.h>

// Dynamic per-group (G=128) asymmetric int8 fake-quantize, fp32 in/out.
// 8192x8192 fp32; groups = 128 contiguous floats = 32 float4s.
// Mapping (round-3 winner): 16 consecutive lanes own one group; each lane
// loads float4 #l and #(l+16) (wave access = 256B segments, measured best).
// NEW: 2-group unroll per iteration (p and p+nthreads) -> 4 independent
// loads in flight, two reduce chains overlapped, butterfly levels shared.
// One IEEE divide per group for inv_scale; dequant folded to a single FMA.
// Requires n8 % (2*nthreads) == 0 (8M % 1M == 0 here).

typedef float f32x4 __attribute__((ext_vector_type(4)));

constexpr float QMIN = -128.0f;
constexpr float QMAX = 127.0f;
constexpr float EPSF = 1.1920928955078125e-07f;  // fp32 eps

__device__ __forceinline__ float min4(f32x4 v) {
  return fminf(fminf(v.x, v.y), fminf(v.z, v.w));
}
__device__ __forceinline__ float max4(f32x4 v) {
  return fmaxf(fmaxf(v.x, v.y), fmaxf(v.z, v.w));
}

__global__ __launch_bounds__(256) void dsq_kernel(
    const float* __restrict__ x, float* __restrict__ out, int n8) {
  const f32x4* __restrict__ x4 = reinterpret_cast<const f32x4*>(x);
  f32x4* __restrict__ o4 = reinterpret_cast<f32x4*>(out);

  int t = blockIdx.x * blockDim.x + threadIdx.x;
  int nthreads = gridDim.x * blockDim.x;

  for (int p = t; p < n8; p += 2 * nthreads) {
    int pA = p;
    int pB = p + nthreads;
    int iA = ((pA >> 4) << 5) + (pA & 15);
    int iB = ((pB >> 4) << 5) + (pB & 15);

    // 4 independent loads in flight
    f32x4 a0 = x4[iA];
    f32x4 a1 = x4[iA + 16];
    f32x4 b0 = x4[iB];
    f32x4 b1 = x4[iB + 16];

    float mnA = fminf(min4(a0), min4(a1));
    float mxA = fmaxf(max4(a0), max4(a1));
    float mnB = fminf(min4(b0), min4(b1));
    float mxB = fmaxf(max4(b0), max4(b1));

    // shared butterfly across the 16 lanes owning each group
    #pragma unroll
    for (int m = 1; m < 16; m <<= 1) {
      mnA = fminf(mnA, __shfl_xor(mnA, m, 64));
      mxA = fmaxf(mxA, __shfl_xor(mxA, m, 64));
      mnB = fminf(mnB, __shfl_xor(mnB, m, 64));
      mxB = fmaxf(mxB, __shfl_xor(mxB, m, 64));
    }

    mnA = fminf(mnA, 0.0f); mxA = fmaxf(mxA, 0.0f);
    mnB = fminf(mnB, 0.0f); mxB = fmaxf(mxB, 0.0f);

    float scA = fmaxf((mxA - mnA) * (1.0f / 255.0f), EPSF);
    float scB = fmaxf((mxB - mnB) * (1.0f / 255.0f), EPSF);
    float invA = 1.0f / scA;
    float invB = 1.0f / scB;
    float zpA = fminf(fmaxf(rintf(QMIN - mnA / scA), QMIN), QMAX);
    float zpB = fminf(fmaxf(rintf(QMIN - mnB / scB), QMIN), QMAX);
    float nzsA = -zpA * scA;
    float nzsB = -zpB * scB;

    f32x4 oa0, oa1, ob0, ob1;
    #define QDQ(e, inv, zp, sc, nzs) \
      fmaf(fminf(fmaxf(rintf((e) * (inv)) + (zp), QMIN), QMAX), (sc), (nzs))
    oa0.x = QDQ(a0.x, invA, zpA, scA, nzsA);
    oa0.y = QDQ(a0.y, invA, zpA, scA, nzsA);
    oa0.z = QDQ(a0.z, invA, zpA, scA, nzsA);
    oa0.w = QDQ(a0.w, invA, zpA, scA, nzsA);
    oa1.x = QDQ(a1.x, invA, zpA, scA, nzsA);
    oa1.y = QDQ(a1.y, invA, zpA, scA, nzsA);
    oa1.z = QDQ(a1.z, invA, zpA, scA, nzsA);
    oa1.w = QDQ(a1.w, invA, zpA, scA, nzsA);
    ob0.x = QDQ(b0.x, invB, zpB, scB, nzsB);
    ob0.y = QDQ(b0.y, invB, zpB, scB, nzsB);
    ob0.z = QDQ(b0.z, invB, zpB, scB, nzsB);
    ob0.w = QDQ(b0.w, invB, zpB, scB, nzsB);
    ob1.x = QDQ(b1.x, invB, zpB, scB, nzsB);
    ob1.y = QDQ(b1.y, invB, zpB, scB, nzsB);
    ob1.z = QDQ(b1.z, invB, zpB, scB, nzsB);
    ob1.w = QDQ(b1.w, invB, zpB, scB, nzsB);
    #undef QDQ

    __builtin_nontemporal_store(oa0, &o4[iA]);
    __builtin_nontemporal_store(oa1, &o4[iA + 16]);
    __builtin_nontemporal_store(ob0, &o4[iB]);
    __builtin_nontemporal_store(ob1, &o4[iB + 16]);
  }
}

extern "C" void kernel_launch(void* const* d_in, const int* in_sizes, int n_in,
                              void* d_out, int out_size, void* d_ws, size_t ws_size,
                              hipStream_t stream) {
  const float* x = (const float*)d_in[0];
  float* out = (float*)d_out;
  int n8 = out_size / 8;  // float4-pairs per group-half: 8 floats per p

  // 2048 blocks x 256 thr = 524288 threads; 8 unrolled iterations each
  dsq_kernel<<<2048, 256, 0, stream>>>(x, out, n8);
}